// Round 10
// baseline (548.104 us; speedup 1.0000x reference)
//
#include <hip/hip_runtime.h>
#include <stdint.h>

typedef unsigned short u16;
typedef __attribute__((ext_vector_type(8))) short s16x8;
typedef __attribute__((ext_vector_type(4))) float f32x4;

// ---------- helpers ----------
__device__ __forceinline__ u16 f2bf(float f) {
  uint32_t u = __float_as_uint(f);
  uint32_t r = (u + 0x7FFFu + ((u >> 16) & 1u)) >> 16;   // RNE
  return (u16)r;
}

__device__ __forceinline__ void gll16(const void* g, void* lds) {
  __builtin_amdgcn_global_load_lds(
      (const __attribute__((address_space(1))) uint32_t*)g,
      (__attribute__((address_space(3))) uint32_t*)lds, 16, 0, 0);
}

// XCD-aware bijective swizzle (grids are multiples of 8)
__device__ __forceinline__ void xcd_swz(int& bx, int& by) {
  int gx = gridDim.x;
  int lin = blockIdx.y * gx + blockIdx.x;
  int cpx = (gx * gridDim.y) >> 3;
  int nl = (lin & 7) * cpx + (lin >> 3);
  bx = nl % gx;
  by = nl / gx;
}

// ---------- fp32 -> bf16 weight convert ----------
__global__ __launch_bounds__(256) void k_f2b(const float* __restrict__ src,
                                             u16* __restrict__ dst, int n) {
  int i = (blockIdx.x * 256 + threadIdx.x) * 4;
  if (i < n) {
    float4 v = *(const float4*)(src + i);
    ushort4 o;
    o.x = f2bf(v.x); o.y = f2bf(v.y); o.z = f2bf(v.z); o.w = f2bf(v.w);
    *(ushort4*)(dst + i) = o;
  }
}

// ---------- fused residual-mix + RMSNorm ----------
template <bool MIX>
__global__ __launch_bounds__(256) void k_rms(const float* __restrict__ X,
                                             const float* __restrict__ X0,
                                             const float* __restrict__ rmix,
                                             float* __restrict__ XMout,
                                             u16* __restrict__ Hout, float eps) {
  const int row = blockIdx.x, t = threadIdx.x;
  const size_t base = (size_t)row * 1024;
  float4 v;
  if (MIX) {
    float4 a = ((const float4*)(X + base))[t];
    float4 b = ((const float4*)(X0 + base))[t];
    float4 c0 = ((const float4*)rmix)[t];
    float4 c1 = ((const float4*)(rmix + 1024))[t];
    v.x = c0.x * a.x + c1.x * b.x;
    v.y = c0.y * a.y + c1.y * b.y;
    v.z = c0.z * a.z + c1.z * b.z;
    v.w = c0.w * a.w + c1.w * b.w;
  } else {
    v = ((const float4*)(X + base))[t];
  }
  float ss = v.x * v.x + v.y * v.y + v.z * v.z + v.w * v.w;
#pragma unroll
  for (int o = 32; o > 0; o >>= 1) ss += __shfl_xor(ss, o);
  __shared__ float red[4];
  if ((t & 63) == 0) red[t >> 6] = ss;
  __syncthreads();
  float tot = red[0] + red[1] + red[2] + red[3];
  float sc = rsqrtf(tot * (1.0f / 1024.0f) + eps);
  if (MIX) ((float4*)(XMout + base))[t] = v;
  ushort4 hv;
  hv.x = f2bf(v.x * sc); hv.y = f2bf(v.y * sc);
  hv.z = f2bf(v.z * sc); hv.w = f2bf(v.w * sc);
  ((ushort4*)(Hout + base))[t] = hv;
}

// ---------- chunked scan over S (16-row chunks) ----------
__global__ __launch_bounds__(256) void k_scan1(const float* __restrict__ P,
                                               float* __restrict__ CS) {
  int blk = blockIdx.x;
  int chunk = blk & 255, b = blk >> 8;
  const float4* p = (const float4*)(P + ((size_t)b * 4096 + chunk * 16) * 1024)
                    + threadIdx.x;
  float4 s = {0.f, 0.f, 0.f, 0.f};
#pragma unroll
  for (int i = 0; i < 16; ++i) {
    float4 v = p[(size_t)i * 256];
    s.x += v.x; s.y += v.y; s.z += v.z; s.w += v.w;
  }
  ((float4*)(CS + ((size_t)b * 256 + chunk) * 1024))[threadIdx.x] = s;
}

__global__ __launch_bounds__(256) void k_scan2(float* __restrict__ CS) {
  int idx = blockIdx.x * 256 + threadIdx.x;  // 4096 column-streams
  int b = idx >> 10, k = idx & 1023;
  float run = 0.f;
  for (int c = 0; c < 256; ++c) {
    size_t o = ((size_t)b * 256 + c) * 1024 + k;
    float v = CS[o];
    CS[o] = run;       // exclusive prefix
    run += v;
  }
}

// ---------- fused scan3 + rmsnorm(memory/denom) -> bf16 m  (wave-only) ----------
__global__ __launch_bounds__(64) void k_scan3f(const float* __restrict__ P,
                                               const float* __restrict__ CS,
                                               u16* __restrict__ Mout) {
  int blk = blockIdx.x;
  int chunk = blk & 255, b = blk >> 8;
  const int t = threadIdx.x;
  const float4* cs4 = (const float4*)(CS + ((size_t)b * 256 + chunk) * 1024);
  float4 run[4];
#pragma unroll
  for (int q = 0; q < 4; ++q) run[q] = cs4[q * 64 + t];
  const float4* p4 = (const float4*)(P + ((size_t)b * 4096 + chunk * 16) * 1024);
  u16* mo = Mout + ((size_t)b * 4096 + chunk * 16) * 1024;
  const int rowbase = chunk * 16;
#pragma unroll 2
  for (int i = 0; i < 16; ++i) {
    float4 v[4];
#pragma unroll
    for (int q = 0; q < 4; ++q) v[q] = p4[(size_t)i * 256 + q * 64 + t];
    const float inv = 1.0f / (float)(rowbase + i + 1);
    float4 y[4];
    float ss = 0.f;
#pragma unroll
    for (int q = 0; q < 4; ++q) {
      run[q].x += v[q].x; run[q].y += v[q].y;
      run[q].z += v[q].z; run[q].w += v[q].w;
      y[q].x = run[q].x * inv; y[q].y = run[q].y * inv;
      y[q].z = run[q].z * inv; y[q].w = run[q].w * inv;
      ss += y[q].x * y[q].x + y[q].y * y[q].y
          + y[q].z * y[q].z + y[q].w * y[q].w;
    }
#pragma unroll
    for (int o = 32; o > 0; o >>= 1) ss += __shfl_xor(ss, o);
    float sc = rsqrtf(ss * (1.0f / 1024.0f) + 1.1920929e-7f);
#pragma unroll
    for (int q = 0; q < 4; ++q) {
      ushort4 hv;
      hv.x = f2bf(y[q].x * sc); hv.y = f2bf(y[q].y * sc);
      hv.z = f2bf(y[q].z * sc); hv.w = f2bf(y[q].w * sc);
      *(ushort4*)(mo + (size_t)i * 1024 + (q * 64 + t) * 4) = hv;
    }
  }
}

// ---------- dual-B GEMM: P = sigmoid(A@Wg^T) * (A@Wu^T)  (R3-proven) ----------
__global__ __launch_bounds__(256, 2) void gemm_dual(
    const u16* __restrict__ A, const u16* __restrict__ Bu,
    const u16* __restrict__ Bg, float* __restrict__ P, int K) {
  __shared__ __align__(16) u16 As[128 * 64];
  __shared__ __align__(16) u16 Us[64 * 64];
  __shared__ __align__(16) u16 Gs[64 * 64];
  const int t = threadIdx.x;
  const int lane = t & 63, wid = t >> 6;
  int bx, by;
  xcd_swz(bx, by);
  const int m0 = by * 128, n0 = bx * 64;
  const int wm = wid * 32;
  const int l15 = lane & 15, lhi = lane >> 4;

  size_t gA[4], gU[2];
#pragma unroll
  for (int i = 0; i < 4; ++i) {
    int j = i * 256 + t;
    int row = j >> 3;
    int k16 = (j & 7) ^ (row & 7);
    gA[i] = (size_t)(m0 + row) * K + k16 * 8;
  }
#pragma unroll
  for (int i = 0; i < 2; ++i) {
    int j = i * 256 + t;
    int row = j >> 3;
    int k16 = (j & 7) ^ (row & 7);
    gU[i] = (size_t)(n0 + row) * K + k16 * 8;
  }

  f32x4 au[2][4], ag[2][4];
#pragma unroll
  for (int mi = 0; mi < 2; ++mi)
#pragma unroll
    for (int ni = 0; ni < 4; ++ni) { au[mi][ni] = 0.0f; ag[mi][ni] = 0.0f; }

  for (int kb = 0; kb < K; kb += 64) {
#pragma unroll
    for (int i = 0; i < 4; ++i) {
      int j = i * 256 + t;
      gll16(A + gA[i] + kb, &As[j * 8]);
    }
#pragma unroll
    for (int i = 0; i < 2; ++i) {
      int j = i * 256 + t;
      gll16(Bu + gU[i] + kb, &Us[j * 8]);
      gll16(Bg + gU[i] + kb, &Gs[j * 8]);
    }
    __syncthreads();
#pragma unroll
    for (int kc = 0; kc < 2; ++kc) {
      s16x8 af[2], uf[4], gf[4];
#pragma unroll
      for (int mi = 0; mi < 2; ++mi) {
        int row = wm + mi * 16 + l15;
        int k16 = (kc * 4 + lhi) ^ (row & 7);
        af[mi] = *(const s16x8*)&As[row * 64 + k16 * 8];
      }
#pragma unroll
      for (int ni = 0; ni < 4; ++ni) {
        int row = ni * 16 + l15;
        int k16 = (kc * 4 + lhi) ^ (row & 7);
        uf[ni] = *(const s16x8*)&Us[row * 64 + k16 * 8];
        gf[ni] = *(const s16x8*)&Gs[row * 64 + k16 * 8];
      }
#pragma unroll
      for (int mi = 0; mi < 2; ++mi)
#pragma unroll
        for (int ni = 0; ni < 4; ++ni) {
          au[mi][ni] = __builtin_amdgcn_mfma_f32_16x16x32_bf16(
              af[mi], uf[ni], au[mi][ni], 0, 0, 0);
          ag[mi][ni] = __builtin_amdgcn_mfma_f32_16x16x32_bf16(
              af[mi], gf[ni], ag[mi][ni], 0, 0, 0);
        }
    }
    __syncthreads();
  }

#pragma unroll
  for (int mi = 0; mi < 2; ++mi) {
    int r0 = m0 + wm + mi * 16 + lhi * 4;
#pragma unroll
    for (int ni = 0; ni < 4; ++ni) {
      int c = n0 + ni * 16 + l15;
#pragma unroll
      for (int j = 0; j < 4; ++j) {
        float u = au[mi][ni][j], g = ag[mi][ni][j];
        P[(size_t)(r0 + j) * 1024 + c] = u / (1.0f + __expf(-g));
      }
    }
  }
}

// ---------- 256x256 BK=64, 8-wave, 4-phase-per-K-tile pipelined GEMM ----------
// Per K-tile kt: 4 sub-phases (kc=sub>>1, mh=sub&1), each {4 A-frag ds_reads
// (+4 B-frag at kc start), stage ONE 16KB half-tile of tile kt+1 (2 gll),
// barriers, 16 MFMA}. LDS = 2 K-tiles ([parity][half][128][64] per matrix).
// Checkpoint once per K-tile at sub0: stage-issue -> vmcnt(2) -> barrier ->
// ds_reads (tile kt validated BEFORE its first reads). Prologue stages tiles
// 0,1 + vmcnt(8). Staging into parity (kt+1)&1 = slots freed after kt-1.
#define SA8(SQ, HF, KB)                                                      \
  { _Pragma("unroll") for (int c = 0; c < 2; ++c)                            \
      gll16(A + aoff[c] + (size_t)(HF) * 128 * lda + (KB),                   \
            (u16*)As + ((SQ) * 2 + (HF)) * 8192 + lo[c]); }
#define SB8(SQ, HF, KB)                                                      \
  { _Pragma("unroll") for (int c = 0; c < 2; ++c)                            \
      gll16(Bw + boff[c] + (size_t)(HF) * 128 * ldb + (KB),                  \
            (u16*)Bs + ((SQ) * 2 + (HF)) * 8192 + lo[c]); }

#define PH8(PAR, KC, MH, CHK0, STGSTMT, VMSTMT)                              \
  {                                                                          \
    if (CHK0) {                                                              \
      STGSTMT;                                                               \
      VMSTMT;                                                                \
      __builtin_amdgcn_s_barrier();                                          \
      __builtin_amdgcn_sched_barrier(0);                                     \
    }                                                                        \
    s16x8 af[4];                                                             \
    _Pragma("unroll") for (int j = 0; j < 4; ++j) {                          \
      int row = ((MH) * 4 + j) * 16 + l15;                                   \
      int cph = (((KC) * 4 + lhi) ^ (row & 7));                              \
      af[j] = *(const s16x8*)((const u16*)As + ((PAR) * 2 + wr) * 8192       \
                              + row * 64 + cph * 8);                         \
    }                                                                        \
    if ((MH) == 0) {                                                         \
      _Pragma("unroll") for (int ni = 0; ni < 4; ++ni) {                     \
        int row = rb + ni * 16 + l15;                                        \
        int cph = (((KC) * 4 + lhi) ^ (row & 7));                            \
        bf[ni] = *(const s16x8*)((const u16*)Bs + ((PAR) * 2 + hb) * 8192    \
                                 + row * 64 + cph * 8);                      \
      }                                                                      \
    }                                                                        \
    if (!(CHK0)) {                                                           \
      STGSTMT;                                                               \
      __builtin_amdgcn_s_barrier();                                          \
    }                                                                        \
    asm volatile("s_waitcnt lgkmcnt(0)" ::: "memory");                       \
    __builtin_amdgcn_sched_barrier(0);                                       \
    __builtin_amdgcn_s_setprio(1);                                           \
    _Pragma("unroll") for (int j = 0; j < 4; ++j)                            \
      _Pragma("unroll") for (int ni = 0; ni < 4; ++ni)                       \
        acc[(MH) * 4 + j][ni] = __builtin_amdgcn_mfma_f32_16x16x32_bf16(     \
            af[j], bf[ni], acc[(MH) * 4 + j][ni], 0, 0, 0);                  \
    __builtin_amdgcn_s_setprio(0);                                           \
    __builtin_amdgcn_s_barrier();                                            \
    __builtin_amdgcn_sched_barrier(0);                                       \
  }

// EPI 1: Cout(f32) = Cadd + colscale[c]*acc ; EPI 2: Cout(bf16) = relu(acc)^2
template <int EPI>
__global__ __launch_bounds__(512, 1) void gemm8p(
    const u16* __restrict__ A, const u16* __restrict__ Bw,
    void* __restrict__ Cout, const float* __restrict__ Cadd,
    const float* __restrict__ colscale, int K, int lda, int ldb, int ldc) {
  __shared__ __align__(16) u16 As[2][2][128][64];  // [parity][half][row][k]
  __shared__ __align__(16) u16 Bs[2][2][128][64];
  const int t = threadIdx.x;
  const int lane = t & 63, wid = t >> 6;
  int bx, by;
  xcd_swz(bx, by);
  const int m0 = by * 256, n0 = bx * 256;
  const int wr = wid >> 2, wc = wid & 3;     // wave -> (2M x 4N)
  const int l15 = lane & 15, lhi = lane >> 4;
  const int hb = wc >> 1;                    // B half this wave reads
  const int rb = (wc & 1) * 64;              // B row base within half

  // staging: 2 chunks/thread per 16KB half-tile; pre-swizzled global source,
  // linear LDS dest (R3/R5-verified, 0 bank conflicts)
  uint32_t aoff[2], boff[2];
  int lo[2];
#pragma unroll
  for (int c = 0; c < 2; ++c) {
    int j = c * 512 + t;
    int row = j >> 3, p8 = j & 7;
    int lg = p8 ^ (row & 7);
    aoff[c] = (uint32_t)(m0 + row) * lda + lg * 8;
    boff[c] = (uint32_t)(n0 + row) * ldb + lg * 8;
    lo[c] = j * 8;
  }

  f32x4 acc[8][4];
#pragma unroll
  for (int mi = 0; mi < 8; ++mi)
#pragma unroll
    for (int ni = 0; ni < 4; ++ni) acc[mi][ni] = 0.0f;

  const int nt = K >> 6;   // #K-tiles (BK=64), nt >= 2

  // prologue: stage tiles 0 (parity 0) and 1 (parity 1); tile 0 landed
#pragma unroll
  for (int kt = 0; kt < 2; ++kt)
#pragma unroll
    for (int hf = 0; hf < 2; ++hf)
#pragma unroll
      for (int c = 0; c < 2; ++c) {
        gll16(A + aoff[c] + (size_t)hf * 128 * lda + kt * 64,
              (u16*)As + (kt * 2 + hf) * 8192 + lo[c]);
        gll16(Bw + boff[c] + (size_t)hf * 128 * ldb + kt * 64,
              (u16*)Bs + (kt * 2 + hf) * 8192 + lo[c]);
      }
  asm volatile("s_waitcnt vmcnt(8)" ::: "memory");
  __builtin_amdgcn_s_barrier();
  __builtin_amdgcn_sched_barrier(0);

  s16x8 bf[4];

  // kt = 0: no staging (prologue staged tiles 0,1), no vmcnt (prologue did it)
  PH8(0, 0, 0, true, , )
  PH8(0, 0, 1, false, , )
  PH8(0, 1, 0, false, , )
  PH8(0, 1, 1, false, , )

  // kt = 1 .. nt-2: stage tile kt+1 into parity (kt+1)&1, vmcnt(2) at sub0
  for (int kt = 1; kt < nt - 1; ++kt) {
    const int par = kt & 1, sq = par ^ 1;
    const uint32_t kb = (uint32_t)(kt + 1) * 64;
    PH8(par, 0, 0, true, SA8(sq, 0, kb),
        asm volatile("s_waitcnt vmcnt(2)" ::: "memory"))
    PH8(par, 0, 1, false, SB8(sq, 0, kb), )
    PH8(par, 1, 0, false, SA8(sq, 1, kb), )
    PH8(par, 1, 1, false, SB8(sq, 1, kb), )
  }

  // kt = nt-1: no staging, drain
  {
    const int par = (nt - 1) & 1;
    PH8(par, 0, 0, true, , asm volatile("s_waitcnt vmcnt(0)" ::: "memory"))
    PH8(par, 0, 1, false, , )
    PH8(par, 1, 0, false, , )
    PH8(par, 1, 1, false, , )
  }

  // epilogue: C/D layout col=lane&15, row=(lane>>4)*4+j
#pragma unroll
  for (int mi = 0; mi < 8; ++mi) {
    int r0 = m0 + wr * 128 + mi * 16 + lhi * 4;
#pragma unroll
    for (int ni = 0; ni < 4; ++ni) {
      int c = n0 + wc * 64 + ni * 16 + l15;
      float cs = (EPI == 1) ? colscale[c] : 0.f;
#pragma unroll
      for (int j = 0; j < 4; ++j) {
        size_t idx = (size_t)(r0 + j) * ldc + c;
        float v = acc[mi][ni][j];
        if (EPI == 1) {
          ((float*)Cout)[idx] = Cadd[idx] + cs * v;
        } else {
          float rv = fmaxf(v, 0.f);
          ((u16*)Cout)[idx] = f2bf(rv * rv);
        }
      }
    }
  }
}

// ---------- launch ----------
extern "C" void kernel_launch(void* const* d_in, const int* in_sizes, int n_in,
                              void* d_out, int out_size, void* d_ws, size_t ws_size,
                              hipStream_t stream) {
  const float* x = (const float*)d_in[0];
  const float* x0 = (const float*)d_in[1];
  const float* Wu = (const float*)d_in[2];
  const float* Wg = (const float*)d_in[3];
  const float* Wo = (const float*)d_in[4];
  const float* Wfc = (const float*)d_in[5];
  const float* Wpj = (const float*)d_in[6];
  const float* mmix = (const float*)d_in[7];
  const float* mscale = (const float*)d_in[8];
  const float* rmix = (const float*)d_in[9];
  float* out = (float*)d_out;

  const int M = 16384;  // B*S
  const size_t MiB = 1024 * 1024;

  // workspace layout (base 154 MiB; fullR2 single-pass proj needs 182 MiB)
  char* ws = (char*)d_ws;
  u16* WuB = (u16*)ws;   ws += 2 * MiB;
  u16* WgB = (u16*)ws;   ws += 2 * MiB;
  u16* WoB = (u16*)ws;   ws += 2 * MiB;
  u16* WfcB = (u16*)ws;  ws += 8 * MiB;
  u16* WpjB = (u16*)ws;  ws += 8 * MiB;
  u16* h = (u16*)ws;     ws += 32 * MiB;                  // h then h2
  char* pool = ws;                                        // 54 MiB in
  float* P = (float*)pool;                                // 64 MiB (gated p)
  float* CS = (float*)(pool + 64 * MiB);                  // 4 MiB chunk sums
  u16* mB = (u16*)(pool + 68 * MiB);                      // 32 MiB normalized mem
  u16* R2 = (u16*)pool;                                   // aliases dead P/CS/mB
  float* xm = out;                                        // xm/x2 lives in d_out

  const bool fullR2 = ws_size >= 182 * MiB;  // R2 = M x 4096 bf16 = 128 MiB

  // weights -> bf16
  k_f2b<<<1024, 256, 0, stream>>>(Wu, WuB, 1024 * 1024);
  k_f2b<<<1024, 256, 0, stream>>>(Wg, WgB, 1024 * 1024);
  k_f2b<<<1024, 256, 0, stream>>>(Wo, WoB, 1024 * 1024);
  k_f2b<<<4096, 256, 0, stream>>>(Wfc, WfcB, 4096 * 1024);
  k_f2b<<<4096, 256, 0, stream>>>(Wpj, WpjB, 4096 * 1024);

  // residual mix + rmsnorm: xm (=out), h
  k_rms<true><<<M, 256, 0, stream>>>(x, x0, rmix, xm, h, 1e-6f);

  // p = sigmoid(h@Wg^T) * (h@Wu^T)
  gemm_dual<<<dim3(16, 128), 256, 0, stream>>>(h, WuB, WgB, P, 1024);

  // memory = cumsum_S(p); m = bf16(rmsnorm(memory/denom))  (fused, wave-only)
  k_scan1<<<1024, 256, 0, stream>>>(P, CS);
  k_scan2<<<16, 256, 0, stream>>>(CS);
  k_scan3f<<<1024, 64, 0, stream>>>(P, CS, mB);

  // x2 = xm + mmix * (m @ Wo^T)   (in-place in d_out)
  gemm8p<1><<<dim3(4, 64), 512, 0, stream>>>(mB, WoB, xm, xm, mmix,
                                             1024, 1024, 1024, 1024);
  // h2 = bf16(rmsnorm(x2))
  k_rms<false><<<M, 256, 0, stream>>>(xm, nullptr, nullptr, nullptr, h, 1e-6f);

  if (fullR2) {
    // R2(full M x 4096) = relu(h2 @ Wfc^T)^2 in ONE dispatch, then K=4096 proj
    gemm8p<2><<<dim3(16, 64), 512, 0, stream>>>(
        h, WfcB, R2, nullptr, nullptr, 1024, 1024, 1024, 4096);
    gemm8p<1><<<dim3(4, 64), 512, 0, stream>>>(
        R2, WpjB, out, out, mscale, 4096, 4096, 4096, 1024);
  } else {
    // MLP in two HID halves; R2 buffer (M x 2048 bf16) reused
    for (int c = 0; c < 2; ++c) {
      gemm8p<2><<<dim3(8, 64), 512, 0, stream>>>(
          h, WfcB + (size_t)c * 2048 * 1024, R2, nullptr, nullptr,
          1024, 1024, 1024, 2048);
      gemm8p<1><<<dim3(4, 64), 512, 0, stream>>>(
          R2, WpjB + (size_t)c * 2048, out, out, mscale,
          2048, 2048, 4096, 1024);
    }
  }
}

// Round 11
// 515.443 us; speedup vs baseline: 1.0634x; 1.0634x over previous
//
#include <hip/hip_runtime.h>
#include <stdint.h>

typedef unsigned short u16;
typedef __attribute__((ext_vector_type(8))) short s16x8;
typedef __attribute__((ext_vector_type(4))) float f32x4;

// ---------- helpers ----------
__device__ __forceinline__ u16 f2bf(float f) {
  uint32_t u = __float_as_uint(f);
  uint32_t r = (u + 0x7FFFu + ((u >> 16) & 1u)) >> 16;   // RNE
  return (u16)r;
}

__device__ __forceinline__ void gll16(const void* g, void* lds) {
  __builtin_amdgcn_global_load_lds(
      (const __attribute__((address_space(1))) uint32_t*)g,
      (__attribute__((address_space(3))) uint32_t*)lds, 16, 0, 0);
}

// XCD-aware bijective swizzle (grids are multiples of 8)
__device__ __forceinline__ void xcd_swz(int& bx, int& by) {
  int gx = gridDim.x;
  int lin = blockIdx.y * gx + blockIdx.x;
  int cpx = (gx * gridDim.y) >> 3;
  int nl = (lin & 7) * cpx + (lin >> 3);
  bx = nl % gx;
  by = nl / gx;
}

// ---------- fp32 -> bf16 weight convert ----------
__global__ __launch_bounds__(256) void k_f2b(const float* __restrict__ src,
                                             u16* __restrict__ dst, int n) {
  int i = (blockIdx.x * 256 + threadIdx.x) * 4;
  if (i < n) {
    float4 v = *(const float4*)(src + i);
    ushort4 o;
    o.x = f2bf(v.x); o.y = f2bf(v.y); o.z = f2bf(v.z); o.w = f2bf(v.w);
    *(ushort4*)(dst + i) = o;
  }
}

// ---------- fused residual-mix + RMSNorm ----------
template <bool MIX>
__global__ __launch_bounds__(256) void k_rms(const float* __restrict__ X,
                                             const float* __restrict__ X0,
                                             const float* __restrict__ rmix,
                                             float* __restrict__ XMout,
                                             u16* __restrict__ Hout, float eps) {
  const int row = blockIdx.x, t = threadIdx.x;
  const size_t base = (size_t)row * 1024;
  float4 v;
  if (MIX) {
    float4 a = ((const float4*)(X + base))[t];
    float4 b = ((const float4*)(X0 + base))[t];
    float4 c0 = ((const float4*)rmix)[t];
    float4 c1 = ((const float4*)(rmix + 1024))[t];
    v.x = c0.x * a.x + c1.x * b.x;
    v.y = c0.y * a.y + c1.y * b.y;
    v.z = c0.z * a.z + c1.z * b.z;
    v.w = c0.w * a.w + c1.w * b.w;
  } else {
    v = ((const float4*)(X + base))[t];
  }
  float ss = v.x * v.x + v.y * v.y + v.z * v.z + v.w * v.w;
#pragma unroll
  for (int o = 32; o > 0; o >>= 1) ss += __shfl_xor(ss, o);
  __shared__ float red[4];
  if ((t & 63) == 0) red[t >> 6] = ss;
  __syncthreads();
  float tot = red[0] + red[1] + red[2] + red[3];
  float sc = rsqrtf(tot * (1.0f / 1024.0f) + eps);
  if (MIX) ((float4*)(XMout + base))[t] = v;
  ushort4 hv;
  hv.x = f2bf(v.x * sc); hv.y = f2bf(v.y * sc);
  hv.z = f2bf(v.z * sc); hv.w = f2bf(v.w * sc);
  ((ushort4*)(Hout + base))[t] = hv;
}

// ---------- scan2: exclusive prefix over 256 chunk-sums per column ----------
__global__ __launch_bounds__(256) void k_scan2(float* __restrict__ CS) {
  int idx = blockIdx.x * 256 + threadIdx.x;  // 4096 column-streams
  int b = idx >> 10, k = idx & 1023;
  float run = 0.f;
  for (int c = 0; c < 256; ++c) {
    size_t o = ((size_t)b * 256 + c) * 1024 + k;
    float v = CS[o];
    CS[o] = run;       // exclusive prefix
    run += v;
  }
}

// ---------- fused scan3 + rmsnorm(memory/denom) -> bf16 m  (wave-only) ----------
// grid 1024 = b(4) x chunk(256); 64 threads; lane owns 16 cols (4x float4).
__global__ __launch_bounds__(64) void k_scan3f(const float* __restrict__ P,
                                               const float* __restrict__ CS,
                                               u16* __restrict__ Mout) {
  int blk = blockIdx.x;
  int chunk = blk & 255, b = blk >> 8;
  const int t = threadIdx.x;
  const float4* cs4 = (const float4*)(CS + ((size_t)b * 256 + chunk) * 1024);
  float4 run[4];
#pragma unroll
  for (int q = 0; q < 4; ++q) run[q] = cs4[q * 64 + t];
  const float4* p4 = (const float4*)(P + ((size_t)b * 4096 + chunk * 16) * 1024);
  u16* mo = Mout + ((size_t)b * 4096 + chunk * 16) * 1024;
  const int rowbase = chunk * 16;
#pragma unroll 2
  for (int i = 0; i < 16; ++i) {
    float4 v[4];
#pragma unroll
    for (int q = 0; q < 4; ++q) v[q] = p4[(size_t)i * 256 + q * 64 + t];
    const float inv = 1.0f / (float)(rowbase + i + 1);
    float4 y[4];
    float ss = 0.f;
#pragma unroll
    for (int q = 0; q < 4; ++q) {
      run[q].x += v[q].x; run[q].y += v[q].y;
      run[q].z += v[q].z; run[q].w += v[q].w;
      y[q].x = run[q].x * inv; y[q].y = run[q].y * inv;
      y[q].z = run[q].z * inv; y[q].w = run[q].w * inv;
      ss += y[q].x * y[q].x + y[q].y * y[q].y
          + y[q].z * y[q].z + y[q].w * y[q].w;
    }
#pragma unroll
    for (int o = 32; o > 0; o >>= 1) ss += __shfl_xor(ss, o);
    float sc = rsqrtf(ss * (1.0f / 1024.0f) + 1.1920929e-7f);
#pragma unroll
    for (int q = 0; q < 4; ++q) {
      ushort4 hv;
      hv.x = f2bf(y[q].x * sc); hv.y = f2bf(y[q].y * sc);
      hv.z = f2bf(y[q].z * sc); hv.w = f2bf(y[q].w * sc);
      *(ushort4*)(mo + (size_t)i * 1024 + (q * 64 + t) * 4) = hv;
    }
  }
}

// ---------- dual-B GEMM: P = sigmoid(A@Wg^T) * (A@Wu^T)  + fused scan1 ----------
// Epilogue also emits 16-row chunk-sums of p into CS (replaces k_scan1):
// per (mi,ni) sum 4 j-values, shfl_xor(16,32) reduces across lhi, lhi==0 writes.
__global__ __launch_bounds__(256, 2) void gemm_dual(
    const u16* __restrict__ A, const u16* __restrict__ Bu,
    const u16* __restrict__ Bg, float* __restrict__ P,
    float* __restrict__ CS, int K) {
  __shared__ __align__(16) u16 As[128 * 64];
  __shared__ __align__(16) u16 Us[64 * 64];
  __shared__ __align__(16) u16 Gs[64 * 64];
  const int t = threadIdx.x;
  const int lane = t & 63, wid = t >> 6;
  int bx, by;
  xcd_swz(bx, by);
  const int m0 = by * 128, n0 = bx * 64;
  const int wm = wid * 32;
  const int l15 = lane & 15, lhi = lane >> 4;

  size_t gA[4], gU[2];
#pragma unroll
  for (int i = 0; i < 4; ++i) {
    int j = i * 256 + t;
    int row = j >> 3;
    int k16 = (j & 7) ^ (row & 7);
    gA[i] = (size_t)(m0 + row) * K + k16 * 8;
  }
#pragma unroll
  for (int i = 0; i < 2; ++i) {
    int j = i * 256 + t;
    int row = j >> 3;
    int k16 = (j & 7) ^ (row & 7);
    gU[i] = (size_t)(n0 + row) * K + k16 * 8;
  }

  f32x4 au[2][4], ag[2][4];
#pragma unroll
  for (int mi = 0; mi < 2; ++mi)
#pragma unroll
    for (int ni = 0; ni < 4; ++ni) { au[mi][ni] = 0.0f; ag[mi][ni] = 0.0f; }

  for (int kb = 0; kb < K; kb += 64) {
#pragma unroll
    for (int i = 0; i < 4; ++i) {
      int j = i * 256 + t;
      gll16(A + gA[i] + kb, &As[j * 8]);
    }
#pragma unroll
    for (int i = 0; i < 2; ++i) {
      int j = i * 256 + t;
      gll16(Bu + gU[i] + kb, &Us[j * 8]);
      gll16(Bg + gU[i] + kb, &Gs[j * 8]);
    }
    __syncthreads();
#pragma unroll
    for (int kc = 0; kc < 2; ++kc) {
      s16x8 af[2], uf[4], gf[4];
#pragma unroll
      for (int mi = 0; mi < 2; ++mi) {
        int row = wm + mi * 16 + l15;
        int k16 = (kc * 4 + lhi) ^ (row & 7);
        af[mi] = *(const s16x8*)&As[row * 64 + k16 * 8];
      }
#pragma unroll
      for (int ni = 0; ni < 4; ++ni) {
        int row = ni * 16 + l15;
        int k16 = (kc * 4 + lhi) ^ (row & 7);
        uf[ni] = *(const s16x8*)&Us[row * 64 + k16 * 8];
        gf[ni] = *(const s16x8*)&Gs[row * 64 + k16 * 8];
      }
#pragma unroll
      for (int mi = 0; mi < 2; ++mi)
#pragma unroll
        for (int ni = 0; ni < 4; ++ni) {
          au[mi][ni] = __builtin_amdgcn_mfma_f32_16x16x32_bf16(
              af[mi], uf[ni], au[mi][ni], 0, 0, 0);
          ag[mi][ni] = __builtin_amdgcn_mfma_f32_16x16x32_bf16(
              af[mi], gf[ni], ag[mi][ni], 0, 0, 0);
        }
    }
    __syncthreads();
  }

#pragma unroll
  for (int mi = 0; mi < 2; ++mi) {
    int r0 = m0 + wm + mi * 16 + lhi * 4;
#pragma unroll
    for (int ni = 0; ni < 4; ++ni) {
      int c = n0 + ni * 16 + l15;
      float ps = 0.f;
#pragma unroll
      for (int j = 0; j < 4; ++j) {
        float u = au[mi][ni][j], g = ag[mi][ni][j];
        float p = u / (1.0f + __expf(-g));
        P[(size_t)(r0 + j) * 1024 + c] = p;
        ps += p;
      }
      // chunk-sum over the 16 rows of this (mi) chunk: reduce across lhi
      ps += __shfl_xor(ps, 16);
      ps += __shfl_xor(ps, 32);
      if (lhi == 0) {
        int grow = m0 + wm + mi * 16;          // 16-aligned global row
        int b = grow >> 12;                    // / 4096
        int chunk = (grow & 4095) >> 4;        // / 16
        CS[((size_t)b * 256 + chunk) * 1024 + c] = ps;
      }
    }
  }
}

// ---------- bf16 MFMA GEMM, 128x128 2-blocks/CU (R3-proven structure) ----------
// C[M,N](ldc) = A[M,K](lda) @ B[N,K](ldb)^T
// EPI 1: Cout(f32) = Cadd + colscale[c]*acc    (in-place Cadd==Cout ok)
// EPI 2: Cout(bf16) = relu(acc)^2
template <int EPI>
__global__ __launch_bounds__(256, 2) void gemm_bf16(
    const u16* __restrict__ A, const u16* __restrict__ Bw, void* __restrict__ Cout,
    const float* __restrict__ Cadd, const float* __restrict__ colscale,
    int K, int lda, int ldb, int ldc) {
  __shared__ __align__(16) u16 As[128 * 64];
  __shared__ __align__(16) u16 Bs[128 * 64];
  const int t = threadIdx.x;
  const int lane = t & 63, wid = t >> 6;
  int bx, by;
  xcd_swz(bx, by);
  const int m0 = by * 128, n0 = bx * 128;
  const int wm = (wid >> 1) * 64, wn = (wid & 1) * 64;
  const int l15 = lane & 15, lhi = lane >> 4;

  size_t gA[4], gB[4];
#pragma unroll
  for (int i = 0; i < 4; ++i) {
    int j = i * 256 + t;
    int row = j >> 3;
    int k16 = (j & 7) ^ (row & 7);
    gA[i] = (size_t)(m0 + row) * lda + k16 * 8;
    gB[i] = (size_t)(n0 + row) * ldb + k16 * 8;
  }

  f32x4 acc[4][4];
#pragma unroll
  for (int mi = 0; mi < 4; ++mi)
#pragma unroll
    for (int ni = 0; ni < 4; ++ni) acc[mi][ni] = 0.0f;

  for (int kb = 0; kb < K; kb += 64) {
#pragma unroll
    for (int i = 0; i < 4; ++i) {
      int j = i * 256 + t;
      gll16(A + gA[i] + kb, &As[j * 8]);
      gll16(Bw + gB[i] + kb, &Bs[j * 8]);
    }
    __syncthreads();
#pragma unroll
    for (int kc = 0; kc < 2; ++kc) {
      s16x8 af[4], bfr[4];
#pragma unroll
      for (int mi = 0; mi < 4; ++mi) {
        int row = wm + mi * 16 + l15;
        int k16 = (kc * 4 + lhi) ^ (row & 7);
        af[mi] = *(const s16x8*)&As[row * 64 + k16 * 8];
      }
#pragma unroll
      for (int ni = 0; ni < 4; ++ni) {
        int row = wn + ni * 16 + l15;
        int k16 = (kc * 4 + lhi) ^ (row & 7);
        bfr[ni] = *(const s16x8*)&Bs[row * 64 + k16 * 8];
      }
#pragma unroll
      for (int mi = 0; mi < 4; ++mi)
#pragma unroll
        for (int ni = 0; ni < 4; ++ni)
          acc[mi][ni] = __builtin_amdgcn_mfma_f32_16x16x32_bf16(
              af[mi], bfr[ni], acc[mi][ni], 0, 0, 0);
    }
    __syncthreads();
  }

#pragma unroll
  for (int mi = 0; mi < 4; ++mi) {
    int r0 = m0 + wm + mi * 16 + lhi * 4;
#pragma unroll
    for (int ni = 0; ni < 4; ++ni) {
      int c = n0 + wn + ni * 16 + l15;
      float cs = (EPI == 1) ? colscale[c] : 0.f;
#pragma unroll
      for (int j = 0; j < 4; ++j) {
        size_t idx = (size_t)(r0 + j) * ldc + c;
        float v = acc[mi][ni][j];
        if (EPI == 1) {
          ((float*)Cout)[idx] = Cadd[idx] + cs * v;
        } else {
          float rv = fmaxf(v, 0.f);
          ((u16*)Cout)[idx] = f2bf(rv * rv);
        }
      }
    }
  }
}

// ---------- launch ----------
extern "C" void kernel_launch(void* const* d_in, const int* in_sizes, int n_in,
                              void* d_out, int out_size, void* d_ws, size_t ws_size,
                              hipStream_t stream) {
  const float* x = (const float*)d_in[0];
  const float* x0 = (const float*)d_in[1];
  const float* Wu = (const float*)d_in[2];
  const float* Wg = (const float*)d_in[3];
  const float* Wo = (const float*)d_in[4];
  const float* Wfc = (const float*)d_in[5];
  const float* Wpj = (const float*)d_in[6];
  const float* mmix = (const float*)d_in[7];
  const float* mscale = (const float*)d_in[8];
  const float* rmix = (const float*)d_in[9];
  float* out = (float*)d_out;

  const int M = 16384;  // B*S
  const size_t MiB = 1024 * 1024;

  // workspace layout (base 154 MiB; fullR2 single-pass proj needs 182 MiB)
  char* ws = (char*)d_ws;
  u16* WuB = (u16*)ws;   ws += 2 * MiB;
  u16* WgB = (u16*)ws;   ws += 2 * MiB;
  u16* WoB = (u16*)ws;   ws += 2 * MiB;
  u16* WfcB = (u16*)ws;  ws += 8 * MiB;
  u16* WpjB = (u16*)ws;  ws += 8 * MiB;
  u16* h = (u16*)ws;     ws += 32 * MiB;                  // h then h2
  char* pool = ws;                                        // 54 MiB in
  float* P = (float*)pool;                                // 64 MiB (gated p)
  float* CS = (float*)(pool + 64 * MiB);                  // 4 MiB chunk sums
  u16* mB = (u16*)(pool + 68 * MiB);                      // 32 MiB normalized mem
  u16* R2 = (u16*)pool;                                   // aliases dead P/CS/mB
  float* xm = out;                                        // xm/x2 lives in d_out

  const bool fullR2 = ws_size >= 182 * MiB;  // R2 = M x 4096 bf16 = 128 MiB

  // weights -> bf16
  k_f2b<<<1024, 256, 0, stream>>>(Wu, WuB, 1024 * 1024);
  k_f2b<<<1024, 256, 0, stream>>>(Wg, WgB, 1024 * 1024);
  k_f2b<<<1024, 256, 0, stream>>>(Wo, WoB, 1024 * 1024);
  k_f2b<<<4096, 256, 0, stream>>>(Wfc, WfcB, 4096 * 1024);
  k_f2b<<<4096, 256, 0, stream>>>(Wpj, WpjB, 4096 * 1024);

  // residual mix + rmsnorm: xm (=out), h
  k_rms<true><<<M, 256, 0, stream>>>(x, x0, rmix, xm, h, 1e-6f);

  // p = sigmoid(h@Wg^T) * (h@Wu^T); chunk-sums (scan1) fused into epilogue
  gemm_dual<<<dim3(16, 128), 256, 0, stream>>>(h, WuB, WgB, P, CS, 1024);

  // memory = cumsum_S(p); m = bf16(rmsnorm(memory/denom))  (fused, wave-only)
  k_scan2<<<16, 256, 0, stream>>>(CS);
  k_scan3f<<<1024, 64, 0, stream>>>(P, CS, mB);

  // x2 = xm + mmix * (m @ Wo^T)   (in-place in d_out)
  gemm_bf16<1><<<dim3(8, 128), 256, 0, stream>>>(mB, WoB, xm, xm, mmix,
                                                 1024, 1024, 1024, 1024);
  // h2 = bf16(rmsnorm(x2))
  k_rms<false><<<M, 256, 0, stream>>>(xm, nullptr, nullptr, nullptr, h, 1e-6f);

  if (fullR2) {
    // R2(full M x 4096) = relu(h2 @ Wfc^T)^2 in ONE dispatch, then K=4096 proj
    gemm_bf16<2><<<dim3(32, 128), 256, 0, stream>>>(
        h, WfcB, R2, nullptr, nullptr, 1024, 1024, 1024, 4096);
    gemm_bf16<1><<<dim3(8, 128), 256, 0, stream>>>(
        R2, WpjB, out, out, mscale, 4096, 4096, 4096, 1024);
  } else {
    // MLP in two HID halves; R2 buffer (M x 2048 bf16) reused
    for (int c = 0; c < 2; ++c) {
      gemm_bf16<2><<<dim3(16, 128), 256, 0, stream>>>(
          h, WfcB + (size_t)c * 2048 * 1024, R2, nullptr, nullptr,
          1024, 1024, 1024, 2048);
      gemm_bf16<1><<<dim3(8, 128), 256, 0, stream>>>(
          R2, WpjB + (size_t)c * 2048, out, out, mscale,
          2048, 2048, 4096, 1024);
    }
  }
}

// Round 12
// 491.560 us; speedup vs baseline: 1.1150x; 1.0486x over previous
//
#include <hip/hip_runtime.h>
#include <stdint.h>

typedef unsigned short u16;
typedef __attribute__((ext_vector_type(8))) short s16x8;
typedef __attribute__((ext_vector_type(4))) float f32x4;

// ---------- helpers ----------
__device__ __forceinline__ u16 f2bf(float f) {
  uint32_t u = __float_as_uint(f);
  uint32_t r = (u + 0x7FFFu + ((u >> 16) & 1u)) >> 16;   // RNE
  return (u16)r;
}

__device__ __forceinline__ float bf2f(u16 h) {
  return __uint_as_float((uint32_t)h << 16);
}

__device__ __forceinline__ void gll16(const void* g, void* lds) {
  __builtin_amdgcn_global_load_lds(
      (const __attribute__((address_space(1))) uint32_t*)g,
      (__attribute__((address_space(3))) uint32_t*)lds, 16, 0, 0);
}

// XCD-aware bijective swizzle (grids are multiples of 8)
__device__ __forceinline__ void xcd_swz(int& bx, int& by) {
  int gx = gridDim.x;
  int lin = blockIdx.y * gx + blockIdx.x;
  int cpx = (gx * gridDim.y) >> 3;
  int nl = (lin & 7) * cpx + (lin >> 3);
  bx = nl % gx;
  by = nl / gx;
}

// ---------- fp32 -> bf16 weight convert, ALL weights in one dispatch ----------
// dst layout (contiguous): [Wu 1M][Wg 1M][Wo 1M][Wfc 4M][Wpj 4M] elements.
// float4 ranges: Wu [0,256K) Wg [256K,512K) Wo [512K,768K)
//                Wfc [768K,1792K) Wpj [1792K,2816K)   (K = 1024 float4s)
__global__ __launch_bounds__(256) void k_f2b5(
    const float* __restrict__ s0, const float* __restrict__ s1,
    const float* __restrict__ s2, const float* __restrict__ s3,
    const float* __restrict__ s4, u16* __restrict__ dst) {
  int i4 = blockIdx.x * 256 + threadIdx.x;   // 11264*256 = 2883584 total
  const float* src;
  int base;
  if (i4 < 262144)       { src = s0; base = 0; }
  else if (i4 < 524288)  { src = s1; base = 262144; }
  else if (i4 < 786432)  { src = s2; base = 524288; }
  else if (i4 < 1835008) { src = s3; base = 786432; }
  else                   { src = s4; base = 1835008; }
  float4 v = ((const float4*)src)[i4 - base];
  ushort4 o;
  o.x = f2bf(v.x); o.y = f2bf(v.y); o.z = f2bf(v.z); o.w = f2bf(v.w);
  ((ushort4*)dst)[i4] = o;
}

// ---------- fused residual-mix + RMSNorm ----------
template <bool MIX>
__global__ __launch_bounds__(256) void k_rms(const float* __restrict__ X,
                                             const float* __restrict__ X0,
                                             const float* __restrict__ rmix,
                                             float* __restrict__ XMout,
                                             u16* __restrict__ Hout, float eps) {
  const int row = blockIdx.x, t = threadIdx.x;
  const size_t base = (size_t)row * 1024;
  float4 v;
  if (MIX) {
    float4 a = ((const float4*)(X + base))[t];
    float4 b = ((const float4*)(X0 + base))[t];
    float4 c0 = ((const float4*)rmix)[t];
    float4 c1 = ((const float4*)(rmix + 1024))[t];
    v.x = c0.x * a.x + c1.x * b.x;
    v.y = c0.y * a.y + c1.y * b.y;
    v.z = c0.z * a.z + c1.z * b.z;
    v.w = c0.w * a.w + c1.w * b.w;
  } else {
    v = ((const float4*)(X + base))[t];
  }
  float ss = v.x * v.x + v.y * v.y + v.z * v.z + v.w * v.w;
#pragma unroll
  for (int o = 32; o > 0; o >>= 1) ss += __shfl_xor(ss, o);
  __shared__ float red[4];
  if ((t & 63) == 0) red[t >> 6] = ss;
  __syncthreads();
  float tot = red[0] + red[1] + red[2] + red[3];
  float sc = rsqrtf(tot * (1.0f / 1024.0f) + eps);
  if (MIX) ((float4*)(XMout + base))[t] = v;
  ushort4 hv;
  hv.x = f2bf(v.x * sc); hv.y = f2bf(v.y * sc);
  hv.z = f2bf(v.z * sc); hv.w = f2bf(v.w * sc);
  ((ushort4*)(Hout + base))[t] = hv;
}

// ---------- scan2: exclusive prefix over 256 chunk-sums per column ----------
// 8-deep load batching: 8 independent loads in flight per group.
__global__ __launch_bounds__(256) void k_scan2(float* __restrict__ CS) {
  int idx = blockIdx.x * 256 + threadIdx.x;  // 4096 column-streams
  int b = idx >> 10, k = idx & 1023;
  float run = 0.f;
  for (int c0 = 0; c0 < 256; c0 += 8) {
    float v[8];
#pragma unroll
    for (int j = 0; j < 8; ++j)
      v[j] = CS[((size_t)b * 256 + c0 + j) * 1024 + k];
#pragma unroll
    for (int j = 0; j < 8; ++j) {
      CS[((size_t)b * 256 + c0 + j) * 1024 + k] = run;  // exclusive prefix
      run += v[j];
    }
  }
}

// ---------- fused scan3 + rmsnorm(memory/denom) -> bf16 m  (wave-only) ----------
// grid 1024 = b(4) x chunk(256); 64 threads; lane owns 16 cols = 2x s16x8.
// P is bf16; accumulation in f32. Row reduce = 6 shfl_xor. No LDS/syncs.
__global__ __launch_bounds__(64) void k_scan3f(const u16* __restrict__ P,
                                               const float* __restrict__ CS,
                                               u16* __restrict__ Mout) {
  int blk = blockIdx.x;
  int chunk = blk & 255, b = blk >> 8;
  const int t = threadIdx.x;
  const float4* cs4 = (const float4*)(CS + ((size_t)b * 256 + chunk) * 1024);
  // lane cols: q0: 8t..8t+7 ; q1: 512+8t..512+8t+7
  float4 run[4];
  run[0] = cs4[2 * t];       run[1] = cs4[2 * t + 1];
  run[2] = cs4[128 + 2 * t]; run[3] = cs4[128 + 2 * t + 1];
  const u16* pr = P + ((size_t)b * 4096 + chunk * 16) * 1024;
  u16* mo = Mout + ((size_t)b * 4096 + chunk * 16) * 1024;
  const int rowbase = chunk * 16;
#pragma unroll 2
  for (int i = 0; i < 16; ++i) {
    s16x8 c0 = *(const s16x8*)(pr + (size_t)i * 1024 + t * 8);
    s16x8 c1 = *(const s16x8*)(pr + (size_t)i * 1024 + 512 + t * 8);
    const float inv = 1.0f / (float)(rowbase + i + 1);
    float y[16];
    float ss = 0.f;
#pragma unroll
    for (int j = 0; j < 4; ++j) {
      run[0][j] += bf2f((u16)c0[j]);
      run[1][j] += bf2f((u16)c0[j + 4]);
      run[2][j] += bf2f((u16)c1[j]);
      run[3][j] += bf2f((u16)c1[j + 4]);
    }
#pragma unroll
    for (int q = 0; q < 4; ++q)
#pragma unroll
      for (int j = 0; j < 4; ++j) {
        float yy = run[q][j] * inv;
        y[q * 4 + j] = yy;
        ss += yy * yy;
      }
#pragma unroll
    for (int o = 32; o > 0; o >>= 1) ss += __shfl_xor(ss, o);
    float sc = rsqrtf(ss * (1.0f / 1024.0f) + 1.1920929e-7f);
    s16x8 o0, o1;
#pragma unroll
    for (int j = 0; j < 4; ++j) {
      o0[j] = (short)f2bf(y[j] * sc);
      o0[j + 4] = (short)f2bf(y[4 + j] * sc);
      o1[j] = (short)f2bf(y[8 + j] * sc);
      o1[j + 4] = (short)f2bf(y[12 + j] * sc);
    }
    *(s16x8*)(mo + (size_t)i * 1024 + t * 8) = o0;
    *(s16x8*)(mo + (size_t)i * 1024 + 512 + t * 8) = o1;
  }
}

// ---------- dual-B GEMM: P(bf16) = sigmoid(A@Wg^T)*(A@Wu^T) + fused scan1 ----------
// Epilogue emits 16-row chunk-sums of p (exact f32) into CS.
__global__ __launch_bounds__(256, 2) void gemm_dual(
    const u16* __restrict__ A, const u16* __restrict__ Bu,
    const u16* __restrict__ Bg, u16* __restrict__ P,
    float* __restrict__ CS, int K) {
  __shared__ __align__(16) u16 As[128 * 64];
  __shared__ __align__(16) u16 Us[64 * 64];
  __shared__ __align__(16) u16 Gs[64 * 64];
  const int t = threadIdx.x;
  const int lane = t & 63, wid = t >> 6;
  int bx, by;
  xcd_swz(bx, by);
  const int m0 = by * 128, n0 = bx * 64;
  const int wm = wid * 32;
  const int l15 = lane & 15, lhi = lane >> 4;

  size_t gA[4], gU[2];
#pragma unroll
  for (int i = 0; i < 4; ++i) {
    int j = i * 256 + t;
    int row = j >> 3;
    int k16 = (j & 7) ^ (row & 7);
    gA[i] = (size_t)(m0 + row) * K + k16 * 8;
  }
#pragma unroll
  for (int i = 0; i < 2; ++i) {
    int j = i * 256 + t;
    int row = j >> 3;
    int k16 = (j & 7) ^ (row & 7);
    gU[i] = (size_t)(n0 + row) * K + k16 * 8;
  }

  f32x4 au[2][4], ag[2][4];
#pragma unroll
  for (int mi = 0; mi < 2; ++mi)
#pragma unroll
    for (int ni = 0; ni < 4; ++ni) { au[mi][ni] = 0.0f; ag[mi][ni] = 0.0f; }

  for (int kb = 0; kb < K; kb += 64) {
#pragma unroll
    for (int i = 0; i < 4; ++i) {
      int j = i * 256 + t;
      gll16(A + gA[i] + kb, &As[j * 8]);
    }
#pragma unroll
    for (int i = 0; i < 2; ++i) {
      int j = i * 256 + t;
      gll16(Bu + gU[i] + kb, &Us[j * 8]);
      gll16(Bg + gU[i] + kb, &Gs[j * 8]);
    }
    __syncthreads();
#pragma unroll
    for (int kc = 0; kc < 2; ++kc) {
      s16x8 af[2], uf[4], gf[4];
#pragma unroll
      for (int mi = 0; mi < 2; ++mi) {
        int row = wm + mi * 16 + l15;
        int k16 = (kc * 4 + lhi) ^ (row & 7);
        af[mi] = *(const s16x8*)&As[row * 64 + k16 * 8];
      }
#pragma unroll
      for (int ni = 0; ni < 4; ++ni) {
        int row = ni * 16 + l15;
        int k16 = (kc * 4 + lhi) ^ (row & 7);
        uf[ni] = *(const s16x8*)&Us[row * 64 + k16 * 8];
        gf[ni] = *(const s16x8*)&Gs[row * 64 + k16 * 8];
      }
#pragma unroll
      for (int mi = 0; mi < 2; ++mi)
#pragma unroll
        for (int ni = 0; ni < 4; ++ni) {
          au[mi][ni] = __builtin_amdgcn_mfma_f32_16x16x32_bf16(
              af[mi], uf[ni], au[mi][ni], 0, 0, 0);
          ag[mi][ni] = __builtin_amdgcn_mfma_f32_16x16x32_bf16(
              af[mi], gf[ni], ag[mi][ni], 0, 0, 0);
        }
    }
    __syncthreads();
  }

#pragma unroll
  for (int mi = 0; mi < 2; ++mi) {
    int r0 = m0 + wm + mi * 16 + lhi * 4;
#pragma unroll
    for (int ni = 0; ni < 4; ++ni) {
      int c = n0 + ni * 16 + l15;
      float ps = 0.f;
#pragma unroll
      for (int j = 0; j < 4; ++j) {
        float u = au[mi][ni][j], g = ag[mi][ni][j];
        float p = u / (1.0f + __expf(-g));
        P[(size_t)(r0 + j) * 1024 + c] = f2bf(p);
        ps += p;
      }
      // chunk-sum over the 16 rows of this (mi) chunk: reduce across lhi
      ps += __shfl_xor(ps, 16);
      ps += __shfl_xor(ps, 32);
      if (lhi == 0) {
        int grow = m0 + wm + mi * 16;          // 16-aligned global row
        int b = grow >> 12;                    // / 4096
        int chunk = (grow & 4095) >> 4;        // / 16
        CS[((size_t)b * 256 + chunk) * 1024 + c] = ps;
      }
    }
  }
}

// ---------- bf16 MFMA GEMM, 128x128 2-blocks/CU (R3-proven structure) ----------
// C[M,N](ldc) = A[M,K](lda) @ B[N,K](ldb)^T
// EPI 1: Cout(f32) = Cadd + colscale[c]*acc    (in-place Cadd==Cout ok)
// EPI 2: Cout(bf16) = relu(acc)^2
template <int EPI>
__global__ __launch_bounds__(256, 2) void gemm_bf16(
    const u16* __restrict__ A, const u16* __restrict__ Bw, void* __restrict__ Cout,
    const float* __restrict__ Cadd, const float* __restrict__ colscale,
    int K, int lda, int ldb, int ldc) {
  __shared__ __align__(16) u16 As[128 * 64];
  __shared__ __align__(16) u16 Bs[128 * 64];
  const int t = threadIdx.x;
  const int lane = t & 63, wid = t >> 6;
  int bx, by;
  xcd_swz(bx, by);
  const int m0 = by * 128, n0 = bx * 128;
  const int wm = (wid >> 1) * 64, wn = (wid & 1) * 64;
  const int l15 = lane & 15, lhi = lane >> 4;

  size_t gA[4], gB[4];
#pragma unroll
  for (int i = 0; i < 4; ++i) {
    int j = i * 256 + t;
    int row = j >> 3;
    int k16 = (j & 7) ^ (row & 7);
    gA[i] = (size_t)(m0 + row) * lda + k16 * 8;
    gB[i] = (size_t)(n0 + row) * ldb + k16 * 8;
  }

  f32x4 acc[4][4];
#pragma unroll
  for (int mi = 0; mi < 4; ++mi)
#pragma unroll
    for (int ni = 0; ni < 4; ++ni) acc[mi][ni] = 0.0f;

  for (int kb = 0; kb < K; kb += 64) {
#pragma unroll
    for (int i = 0; i < 4; ++i) {
      int j = i * 256 + t;
      gll16(A + gA[i] + kb, &As[j * 8]);
      gll16(Bw + gB[i] + kb, &Bs[j * 8]);
    }
    __syncthreads();
#pragma unroll
    for (int kc = 0; kc < 2; ++kc) {
      s16x8 af[4], bfr[4];
#pragma unroll
      for (int mi = 0; mi < 4; ++mi) {
        int row = wm + mi * 16 + l15;
        int k16 = (kc * 4 + lhi) ^ (row & 7);
        af[mi] = *(const s16x8*)&As[row * 64 + k16 * 8];
      }
#pragma unroll
      for (int ni = 0; ni < 4; ++ni) {
        int row = wn + ni * 16 + l15;
        int k16 = (kc * 4 + lhi) ^ (row & 7);
        bfr[ni] = *(const s16x8*)&Bs[row * 64 + k16 * 8];
      }
#pragma unroll
      for (int mi = 0; mi < 4; ++mi)
#pragma unroll
        for (int ni = 0; ni < 4; ++ni)
          acc[mi][ni] = __builtin_amdgcn_mfma_f32_16x16x32_bf16(
              af[mi], bfr[ni], acc[mi][ni], 0, 0, 0);
    }
    __syncthreads();
  }

#pragma unroll
  for (int mi = 0; mi < 4; ++mi) {
    int r0 = m0 + wm + mi * 16 + lhi * 4;
#pragma unroll
    for (int ni = 0; ni < 4; ++ni) {
      int c = n0 + wn + ni * 16 + l15;
      float cs = (EPI == 1) ? colscale[c] : 0.f;
#pragma unroll
      for (int j = 0; j < 4; ++j) {
        size_t idx = (size_t)(r0 + j) * ldc + c;
        float v = acc[mi][ni][j];
        if (EPI == 1) {
          ((float*)Cout)[idx] = Cadd[idx] + cs * v;
        } else {
          float rv = fmaxf(v, 0.f);
          ((u16*)Cout)[idx] = f2bf(rv * rv);
        }
      }
    }
  }
}

// ---------- launch ----------
extern "C" void kernel_launch(void* const* d_in, const int* in_sizes, int n_in,
                              void* d_out, int out_size, void* d_ws, size_t ws_size,
                              hipStream_t stream) {
  const float* x = (const float*)d_in[0];
  const float* x0 = (const float*)d_in[1];
  const float* Wu = (const float*)d_in[2];
  const float* Wg = (const float*)d_in[3];
  const float* Wo = (const float*)d_in[4];
  const float* Wfc = (const float*)d_in[5];
  const float* Wpj = (const float*)d_in[6];
  const float* mmix = (const float*)d_in[7];
  const float* mscale = (const float*)d_in[8];
  const float* rmix = (const float*)d_in[9];
  float* out = (float*)d_out;

  const int M = 16384;  // B*S
  const size_t MiB = 1024 * 1024;

  // workspace layout: weights 22 + h 32 + pool (128 for full R2) = 182 MiB.
  // P(bf16 32) / CS(4) / mB(32) live inside the pool; R2 aliases them (dead).
  char* ws = (char*)d_ws;
  u16* WuB = (u16*)ws;   ws += 2 * MiB;
  u16* WgB = (u16*)ws;   ws += 2 * MiB;
  u16* WoB = (u16*)ws;   ws += 2 * MiB;
  u16* WfcB = (u16*)ws;  ws += 8 * MiB;
  u16* WpjB = (u16*)ws;  ws += 8 * MiB;
  u16* h = (u16*)ws;     ws += 32 * MiB;                  // h then h2
  char* pool = ws;                                        // 54 MiB in
  u16* P = (u16*)pool;                                    // 32 MiB (bf16 p)
  float* CS = (float*)(pool + 32 * MiB);                  // 4 MiB chunk sums
  u16* mB = (u16*)(pool + 36 * MiB);                      // 32 MiB normalized mem
  u16* R2 = (u16*)pool;                                   // aliases dead P/CS/mB
  float* xm = out;                                        // xm/x2 lives in d_out

  const bool fullR2 = ws_size >= 182 * MiB;  // R2 = M x 4096 bf16 = 128 MiB

  // all weights -> bf16 in ONE dispatch (contiguous dst = WuB..WpjB)
  k_f2b5<<<11264, 256, 0, stream>>>(Wu, Wg, Wo, Wfc, Wpj, WuB);

  // residual mix + rmsnorm: xm (=out), h
  k_rms<true><<<M, 256, 0, stream>>>(x, x0, rmix, xm, h, 1e-6f);

  // p = sigmoid(h@Wg^T) * (h@Wu^T); chunk-sums (scan1) fused into epilogue
  gemm_dual<<<dim3(16, 128), 256, 0, stream>>>(h, WuB, WgB, P, CS, 1024);

  // memory = cumsum_S(p); m = bf16(rmsnorm(memory/denom))  (fused, wave-only)
  k_scan2<<<16, 256, 0, stream>>>(CS);
  k_scan3f<<<1024, 64, 0, stream>>>(P, CS, mB);

  // x2 = xm + mmix * (m @ Wo^T)   (in-place in d_out)
  gemm_bf16<1><<<dim3(8, 128), 256, 0, stream>>>(mB, WoB, xm, xm, mmix,
                                                 1024, 1024, 1024, 1024);
  // h2 = bf16(rmsnorm(x2))
  k_rms<false><<<M, 256, 0, stream>>>(xm, nullptr, nullptr, nullptr, h, 1e-6f);

  if (fullR2) {
    // R2(full M x 4096) = relu(h2 @ Wfc^T)^2 in ONE dispatch, then K=4096 proj
    gemm_bf16<2><<<dim3(32, 128), 256, 0, stream>>>(
        h, WfcB, R2, nullptr, nullptr, 1024, 1024, 1024, 4096);
    gemm_bf16<1><<<dim3(8, 128), 256, 0, stream>>>(
        R2, WpjB, out, out, mscale, 4096, 4096, 4096, 1024);
  } else {
    // MLP in two HID halves; R2 buffer (M x 2048 bf16) reused
    for (int c = 0; c < 2; ++c) {
      gemm_bf16<2><<<dim3(16, 128), 256, 0, stream>>>(
          h, WfcB + (size_t)c * 2048 * 1024, R2, nullptr, nullptr,
          1024, 1024, 1024, 2048);
      gemm_bf16<1><<<dim3(8, 128), 256, 0, stream>>>(
          R2, WpjB + (size_t)c * 2048, out, out, mscale,
          2048, 2048, 4096, 1024);
    }
  }
}